// Round 5
// baseline (413.268 us; speedup 1.0000x reference)
//
#include <hip/hip_runtime.h>
#include <hip/hip_cooperative_groups.h>
#include <math.h>

namespace cg = cooperative_groups;

#define HID   128
#define NRAD  6
#define TABN  4096          // nearest-neighbor table rows 0..TABN (row TABN = 0, x>=1 gate)
#define CUTOFF_INV 0.2f
#define MZ    95
#define GRID  256           // 1 block/CU -> cooperative co-residency guaranteed
#define BLK   1024
#define NPAD  (GRID * 512)  // 131072; scan chunk = 512 ints/block

typedef unsigned int uint32;

__global__ __launch_bounds__(BLK, 4)
void mega(const int* __restrict__ zt, const float* __restrict__ pos,
          const int* __restrict__ ei, const float* __restrict__ freq,
          const float* __restrict__ emb, const float* __restrict__ W_rbf,
          const float* __restrict__ b_rbf, const float* __restrict__ W_lin,
          const float* __restrict__ b_lin,
          float* __restrict__ Tf, float* __restrict__ ftab,
          int* __restrict__ cnt, int* __restrict__ offs, int* __restrict__ cursor,
          int* __restrict__ bsum, int* __restrict__ payload,
          float* __restrict__ out, int N, int E, int MAXZ)
{
    cg::grid_group grid = cg::this_grid();
    __shared__ uint32 sBuf[2 * MZ * (HID / 2)];   // 48640 B: P0 = hrs staging, P4 = bf16 tables
    __shared__ int sEx[128];
    __shared__ int sW[2];
    __shared__ int sRed[16];
    __shared__ int sBase;

    const int tid = threadIdx.x, bid = blockIdx.x;

    // ========== P0: zero cnt + build ftab / T1 / T2 ==========
    {
        int i4 = bid * BLK + tid;
        if (i4 < NPAD / 4) ((int4*)cnt)[i4] = make_int4(0, 0, 0, 0);
    }
    float* hrs = (float*)sBuf;
    if (bid < 129) {
        // ftab rows [bid*32, bid*32+32): stage silu(rbf@W_rbf+b) in LDS, then GEMV vs W3
        int rbase = bid * 32;
        int h  = tid & (HID - 1);
        int rg = tid >> 7;                   // 8 row-groups x 128 threads
        for (int ri = 0; ri < 4; ++ri) {
            int r   = rg * 4 + ri;
            int row = rbase + r;
            if (row <= TABN) {
                float rbf[NRAD];
                if (row == 0) {
#pragma unroll
                    for (int k = 0; k < NRAD; ++k) rbf[k] = freq[k];      // lim x->0
                } else if (row >= TABN) {
#pragma unroll
                    for (int k = 0; k < NRAD; ++k) rbf[k] = 0.f;          // envelope gate
                } else {
                    float x  = (float)row / (float)TABN;
                    float x2 = x * x, x5 = x2 * x2 * x;
                    float env = 1.f / x + x5 * (-28.f + x * (48.f + x * (-21.f)));
#pragma unroll
                    for (int k = 0; k < NRAD; ++k) rbf[k] = env * sinf(freq[k] * x);
                }
                float pre = b_rbf[h];
#pragma unroll
                for (int k = 0; k < NRAD; ++k) pre = fmaf(rbf[k], W_rbf[k * HID + h], pre);
                hrs[r * HID + h] = pre / (1.f + __expf(-pre));
            }
        }
        __syncthreads();
        const float* W3 = W_lin + (size_t)2 * HID * HID;
        float a0 = 0, a1 = 0, a2 = 0, a3 = 0;
        int r0 = rg * 4;
#pragma unroll 4
        for (int k = 0; k < HID; ++k) {
            float w = W3[k * HID + h];
            a0 = fmaf(hrs[(r0 + 0) * HID + k], w, a0);
            a1 = fmaf(hrs[(r0 + 1) * HID + k], w, a1);
            a2 = fmaf(hrs[(r0 + 2) * HID + k], w, a2);
            a3 = fmaf(hrs[(r0 + 3) * HID + k], w, a3);
        }
        int g = rbase + r0;
        if (g     <= TABN) ftab[(size_t)(g    ) * HID + h] = a0;
        if (g + 1 <= TABN) ftab[(size_t)(g + 1) * HID + h] = a1;
        if (g + 2 <= TABN) ftab[(size_t)(g + 2) * HID + h] = a2;
        if (g + 3 <= TABN) ftab[(size_t)(g + 3) * HID + h] = a3;
    } else if (bid - 129 < MAXZ) {
        // T1 (s=0, +b_lin) and T2 (s=1) for z = bid-129, fp32 to ws
        int zz = bid - 129;
        if (tid < HID) hrs[tid] = emb[zz * HID + tid];
        __syncthreads();
        if (tid < 2 * HID) {
            int h = tid & (HID - 1), s = tid >> 7;
            const float* W = W_lin + (size_t)s * HID * HID;
            float acc = (s == 0) ? b_lin[h] : 0.f;
#pragma unroll 8
            for (int k = 0; k < HID; ++k) acc = fmaf(hrs[k], W[k * HID + h], acc);
            Tf[(size_t)(s * MAXZ + zz) * HID + h] = acc;
        }
    }
    grid.sync();

    // ========== P1: degree count ==========
    {
        const int* ej = ei + E;
        int nQ = E >> 2;
        for (int q = bid * BLK + tid; q < nQ; q += GRID * BLK) {
            int4 v = ((const int4*)ej)[q];
            atomicAdd(&cnt[v.x], 1); atomicAdd(&cnt[v.y], 1);
            atomicAdd(&cnt[v.z], 1); atomicAdd(&cnt[v.w], 1);
        }
        for (int e = (nQ << 2) + bid * BLK + tid; e < E; e += GRID * BLK)
            atomicAdd(&cnt[ej[e]], 1);
    }
    grid.sync();

    // ========== P2a: block-local scan of this block's 512-int chunk ==========
    int incl = 0, t3 = 0;
    {
        int lane = tid & 63;
        if (tid < 128) {
            int4 v = ((const int4*)cnt)[bid * 128 + tid];
            t3 = v.x + v.y + v.z + v.w;
            incl = t3;
#pragma unroll
            for (int o = 1; o < 64; o <<= 1) {
                int u = __shfl_up(incl, o, 64);
                if (lane >= o) incl += u;
            }
            if (lane == 63) sW[tid >> 6] = incl;
        }
        __syncthreads();
        if (tid < 128) {
            if (tid >= 64) incl += sW[0];
            sEx[tid] = incl - t3;              // exclusive within chunk
            if (tid == 127) bsum[bid] = incl;  // chunk total
        }
    }
    grid.sync();

    // ========== P2b: base = sum(bsum[0..bid)), write offs + cursor ==========
    {
        int v = 0;
        if (tid < GRID && tid < bid) v = bsum[tid];
#pragma unroll
        for (int o = 32; o > 0; o >>= 1) v += __shfl_down(v, o, 64);
        if ((tid & 63) == 0) sRed[tid >> 6] = v;
        __syncthreads();
        if (tid == 0) { int b = 0; for (int w = 0; w < 16; ++w) b += sRed[w]; sBase = b; }
        __syncthreads();
        if (tid < 128) {
            int4 v4 = ((const int4*)cnt)[bid * 128 + tid];
            int base = sBase + sEx[tid];
            int4 o;
            o.x = base; o.y = base + v4.x; o.z = o.y + v4.y; o.w = o.z + v4.z;
            ((int4*)offs)[bid * 128 + tid]   = o;
            ((int4*)cursor)[bid * 128 + tid] = o;
        }
    }
    grid.sync();

    // ========== P3: scatter packed payload {ti:13 | zi:7 | zj:7} ==========
    {
        auto one = [&](int i, int j) {
            float dx = pos[3 * i]     - pos[3 * j];
            float dy = pos[3 * i + 1] - pos[3 * j + 1];
            float dz = pos[3 * i + 2] - pos[3 * j + 2];
            float d  = sqrtf(dx * dx + dy * dy + dz * dz);
            float u  = fminf(d * CUTOFF_INV, 1.0f) * (float)TABN;
            int   ti = (int)(u + 0.5f);
            if (ti > TABN) ti = TABN;
            int pl = ti | (zt[i] << 13) | (zt[j] << 20);
            payload[atomicAdd(&cursor[j], 1)] = pl;
        };
        int nQ = E >> 2;
        for (int q = bid * BLK + tid; q < nQ; q += GRID * BLK) {
            int4 iv = ((const int4*)ei)[q];
            int4 jv = ((const int4*)(ei + E))[q];
            one(iv.x, jv.x); one(iv.y, jv.y); one(iv.z, jv.z); one(iv.w, jv.w);
        }
        for (int e = (nQ << 2) + bid * BLK + tid; e < E; e += GRID * BLK)
            one(ei[e], ei[E + e]);
    }
    grid.sync();

    // ========== P4: pack fp32 tables -> bf16 pairs in LDS, gather 1 wave/node ==========
    {
        int nU = 2 * MAXZ * (HID / 2);
        for (int u = tid; u < nU; u += BLK) {
            float2 f = ((const float2*)Tf)[u];
            uint32 a = (__float_as_uint(f.x) + 0x8000u) >> 16;           // low 16: even h
            uint32 b = (__float_as_uint(f.y) + 0x8000u) & 0xFFFF0000u;   // high 16: odd h
            sBuf[u] = a | b;
        }
        __syncthreads();
        int wv = tid >> 6, lane = tid & 63;
        const uint32* sT2 = sBuf + MAXZ * (HID / 2);
        int h2 = lane * 2;
        for (int n = bid * 16 + wv; n < N; n += GRID * 16) {
            int beg = __builtin_amdgcn_readfirstlane(offs[n]);
            int end = __builtin_amdgcn_readfirstlane(offs[n + 1]);
            float a0 = 0.f, a1 = 0.f;
            auto body = [&](int e) {
                int pl = __builtin_amdgcn_readfirstlane(payload[e]);
                int ti = pl & 0x1FFF;
                int zi = (pl >> 13) & 0x7F;
                int zj = (pl >> 20) & 0x7F;
                float2 f  = *(const float2*)(ftab + (size_t)ti * HID + h2);
                uint32 u1 = sBuf[zi * (HID / 2) + lane];
                uint32 u2 = sT2[zj * (HID / 2) + lane];
                float p0 = __uint_as_float(u1 << 16)          + __uint_as_float(u2 << 16)          + f.x;
                float p1 = __uint_as_float(u1 & 0xFFFF0000u)  + __uint_as_float(u2 & 0xFFFF0000u)  + f.y;
                a0 = fmaf(p0, __builtin_amdgcn_rcpf(1.f + __expf(-p0)), a0);
                a1 = fmaf(p1, __builtin_amdgcn_rcpf(1.f + __expf(-p1)), a1);
            };
            int e = beg;
            for (; e + 1 < end; e += 2) { body(e); body(e + 1); }
            if (e < end) body(e);
            float s = (end > beg) ? 1.0f / (float)(end - beg) : 0.0f;
            float2 o; o.x = a0 * s; o.y = a1 * s;
            *(float2*)(out + (size_t)n * HID + h2) = o;
        }
    }
}

// ---------------- launch ----------------
extern "C" void kernel_launch(void* const* d_in, const int* in_sizes, int n_in,
                              void* d_out, int out_size, void* d_ws, size_t ws_size,
                              hipStream_t stream) {
    const int*   z     = (const int*)d_in[0];
    const float* pos   = (const float*)d_in[1];
    const int*   ei    = (const int*)d_in[2];
    const float* freq  = (const float*)d_in[3];
    const float* emb   = (const float*)d_in[4];
    const float* W_rbf = (const float*)d_in[5];
    const float* b_rbf = (const float*)d_in[6];
    const float* W_lin = (const float*)d_in[7];
    const float* b_lin = (const float*)d_in[8];

    int N    = in_sizes[0];
    int E    = in_sizes[2] / 2;
    int MAXZ = in_sizes[4] / HID;   // 95 == MZ
    float* out = (float*)d_out;

    char* ws = (char*)d_ws;
    size_t off = 0;
    auto alloc = [&](size_t bytes) { char* p = ws + off; off = (off + bytes + 255) & ~(size_t)255; return p; };
    float* Tf      = (float*)alloc((size_t)2 * MAXZ * HID * 4);
    float* ftab    = (float*)alloc((size_t)(TABN + 1) * HID * 4);
    int*   cnt     = (int*)alloc((size_t)NPAD * 4);
    int*   offs    = (int*)alloc((size_t)(NPAD + 4) * 4);
    int*   cursor  = (int*)alloc((size_t)(NPAD + 4) * 4);
    int*   bsum    = (int*)alloc((size_t)GRID * 4);
    int*   payload = (int*)alloc((size_t)E * 4);

    void* args[] = {(void*)&z, (void*)&pos, (void*)&ei, (void*)&freq, (void*)&emb,
                    (void*)&W_rbf, (void*)&b_rbf, (void*)&W_lin, (void*)&b_lin,
                    (void*)&Tf, (void*)&ftab, (void*)&cnt, (void*)&offs, (void*)&cursor,
                    (void*)&bsum, (void*)&payload, (void*)&out,
                    (void*)&N, (void*)&E, (void*)&MAXZ};
    hipLaunchCooperativeKernel((const void*)mega, dim3(GRID), dim3(BLK), args, 0, stream);
}

// Round 6
// 214.143 us; speedup vs baseline: 1.9299x; 1.9299x over previous
//
#include <hip/hip_runtime.h>
#include <hip/hip_bf16.h>
#include <math.h>

#define HID 128
#define NRAD 6
#define TABN 4096          // nearest-neighbor table rows 0..TABN (row TABN = 0, x>=1 gate)
#define CUTOFF_INV 0.2f
#define MZ 95

typedef unsigned int uint32;

// ---------- K1: T1(+b_lin)/T2 bf16 tables + ftab + degree count + rank ----------
__global__ void build1(const float* __restrict__ emb, const float* __restrict__ W_lin,
                       const float* __restrict__ freq, const float* __restrict__ W_rbf,
                       const float* __restrict__ b_rbf, const float* __restrict__ b_lin,
                       __hip_bfloat16* __restrict__ Tb, float* __restrict__ ftab,
                       const int* __restrict__ ej, int* __restrict__ cnt,
                       int* __restrict__ rank, int MAXZ, int E) {
    __shared__ float sh[HID];
    int h   = threadIdx.x;
    int bid = blockIdx.x;
    int nT  = 2 * MAXZ;
    int nF  = TABN + 1;
    if (bid < nT) {
        int zz = bid >> 1, s = bid & 1;
        sh[h] = emb[zz * HID + h];
        __syncthreads();
        const float* W = W_lin + (size_t)s * HID * HID;
        float acc = (s == 0) ? b_lin[h] : 0.f;   // fold bias into T1
#pragma unroll 8
        for (int k = 0; k < HID; ++k) acc = fmaf(sh[k], W[k * HID + h], acc);
        Tb[(size_t)(s * MAXZ + zz) * HID + h] = __float2bfloat16(acc);
    } else if (bid < nT + nF) {
        int t = bid - nT;   // 0..TABN
        float rbf[NRAD];
        if (t == 0) {
#pragma unroll
            for (int k = 0; k < NRAD; ++k) rbf[k] = freq[k];   // lim x->0 env*sin(fx)=f
        } else if (t >= TABN) {
#pragma unroll
            for (int k = 0; k < NRAD; ++k) rbf[k] = 0.f;       // envelope gate x>=1
        } else {
            float x  = (float)t / (float)TABN;
            float x2 = x * x, x5 = x2 * x2 * x;
            float env = 1.f / x + x5 * (-28.f + x * (48.f + x * (-21.f)));
#pragma unroll
            for (int k = 0; k < NRAD; ++k) rbf[k] = env * sinf(freq[k] * x);
        }
        float pre = b_rbf[h];
#pragma unroll
        for (int k = 0; k < NRAD; ++k) pre = fmaf(rbf[k], W_rbf[k * HID + h], pre);
        sh[h] = pre / (1.f + __expf(-pre));   // precise silu (once per table row)
        __syncthreads();
        const float* W3 = W_lin + (size_t)2 * HID * HID;
        float acc = 0.f;
#pragma unroll 8
        for (int k = 0; k < HID; ++k) acc = fmaf(sh[k], W3[k * HID + h], acc);
        ftab[(size_t)t * HID + h] = acc;
    } else {
        int e = (bid - nT - nF) * HID + h;
        if (e < E) rank[e] = atomicAdd(&cnt[ej[e]], 1);   // degree + stable slot rank
    }
}

// ---------- scan: 1024 elems/block, 256 threads, shfl-based ----------
__global__ void scan1(const int* __restrict__ cnt, int* __restrict__ offs,
                      int* __restrict__ bsum) {
    int t = threadIdx.x;
    size_t base = (size_t)blockIdx.x * 1024 + t * 4;
    int4 v = *(const int4*)(cnt + base);
    int s0 = v.x, s1 = s0 + v.y, s2 = s1 + v.z, s3 = s2 + v.w;
    int lane = t & 63, wv = t >> 6;
    int incl = s3;
#pragma unroll
    for (int off = 1; off < 64; off <<= 1) {
        int u = __shfl_up(incl, off, 64);
        if (lane >= off) incl += u;
    }
    __shared__ int ws[4];
    if (lane == 63) ws[wv] = incl;
    __syncthreads();
    int wbase = 0;
    for (int w = 0; w < wv; ++w) wbase += ws[w];
    int ex = wbase + incl - s3;
    int4 o;
    o.x = ex; o.y = ex + s0; o.z = ex + s1; o.w = ex + s2;
    *(int4*)(offs + base) = o;
    if (t == 255) bsum[blockIdx.x] = wbase + incl;
}

__global__ void scan2(int* __restrict__ bsum, int NB) {   // 1 block, NB<=256
    int t = threadIdx.x;
    int v = (t < NB) ? bsum[t] : 0;
    int lane = t & 63, wv = t >> 6;
    int incl = v;
#pragma unroll
    for (int off = 1; off < 64; off <<= 1) {
        int u = __shfl_up(incl, off, 64);
        if (lane >= off) incl += u;
    }
    __shared__ int ws[4];
    if (lane == 63) ws[wv] = incl;
    __syncthreads();
    int wbase = 0;
    for (int w = 0; w < wv; ++w) wbase += ws[w];
    if (t < NB) bsum[t] = wbase + incl - v;
}

__global__ void scan3(int* __restrict__ offs, const int* __restrict__ bsum) {
    size_t base = (size_t)blockIdx.x * 1024 + threadIdx.x * 4;
    int add = bsum[blockIdx.x];
    int4 o = *(int4*)(offs + base);
    o.x += add; o.y += add; o.z += add; o.w += add;
    *(int4*)(offs + base) = o;
}

// ---------- scatter: no atomics; slot = offs[j] + rank[e]; payload {ti:13|zi:7|zj:7} ----------
__global__ void scatter_k(const int* __restrict__ ei, const float* __restrict__ pos,
                          const int* __restrict__ z, const int* __restrict__ offs,
                          const int* __restrict__ rank, int* __restrict__ payload, int E) {
    int e = blockIdx.x * 256 + threadIdx.x;
    if (e >= E) return;
    int i = ei[e];
    int j = ei[E + e];
    float dx = pos[3 * i]     - pos[3 * j];
    float dy = pos[3 * i + 1] - pos[3 * j + 1];
    float dz = pos[3 * i + 2] - pos[3 * j + 2];
    float d  = sqrtf(dx * dx + dy * dy + dz * dz);
    float u  = fminf(d * CUTOFF_INV, 1.0f) * (float)TABN;
    int   ti = (int)(u + 0.5f);          // nearest
    if (ti > TABN) ti = TABN;
    int pl = ti | (z[i] << 13) | (z[j] << 20);
    payload[offs[j] + rank[e]] = pl;
}

// ---------- gather: 1 wave (64 lanes) per node; batched payload via readlane ----------
__launch_bounds__(1024)
__global__ void gather_k(const int* __restrict__ offs, const int* __restrict__ payload,
                         const uint32* __restrict__ Tb32, const float* __restrict__ ftab,
                         float* __restrict__ out, int N) {
    __shared__ uint32 sT[2 * MZ * (HID / 2)];    // 48640 B, bf16 pairs
    int tid = threadIdx.x;
    for (int k = tid; k < 2 * MZ * (HID / 2); k += 1024) sT[k] = Tb32[k];
    __syncthreads();

    int lane = tid & 63, wv = tid >> 6;          // 16 waves/block, 1 node/wave
    int h2   = lane * 2;
    const uint32* sT2 = sT + MZ * (HID / 2);
    const float*  ft  = ftab + h2;
    int nCh = (N + 15) >> 4;

    for (int ch = blockIdx.x; ch < nCh; ch += gridDim.x) {
        int n = (ch << 4) + wv;
        if (n >= N) continue;
        int beg = offs[n];
        int end = offs[n + 1];

        float a0 = 0.f, a1 = 0.f;
        for (int base = beg; base < end; base += 64) {
            int rem = end - base;
            int cb  = rem < 64 ? rem : 64;
            int plv = payload[base + (lane < cb ? lane : cb - 1)];   // one coalesced load
            for (int k = 0; k < cb; ++k) {
                int pl = __builtin_amdgcn_readlane(plv, k);          // SGPR broadcast
                int ti = pl & 0x1FFF;
                int zi = (pl >> 13) & 0x7F;
                int zj = (pl >> 20) & 0x7F;
                float2 f  = *(const float2*)(ft + (size_t)ti * HID);
                uint32 u1 = sT[zi * (HID / 2) + lane];
                uint32 u2 = sT2[zj * (HID / 2) + lane];
                float p0 = __uint_as_float(u1 << 16)         + __uint_as_float(u2 << 16)         + f.x;
                float p1 = __uint_as_float(u1 & 0xFFFF0000u) + __uint_as_float(u2 & 0xFFFF0000u) + f.y;
                a0 = fmaf(p0, __builtin_amdgcn_rcpf(1.f + __expf(-p0)), a0);
                a1 = fmaf(p1, __builtin_amdgcn_rcpf(1.f + __expf(-p1)), a1);
            }
        }
        float s = (end > beg) ? 1.0f / (float)(end - beg) : 0.0f;
        float2 o; o.x = a0 * s; o.y = a1 * s;
        *(float2*)(out + (size_t)n * HID + h2) = o;
    }
}

// ---------- launch ----------
extern "C" void kernel_launch(void* const* d_in, const int* in_sizes, int n_in,
                              void* d_out, int out_size, void* d_ws, size_t ws_size,
                              hipStream_t stream) {
    const int*   z     = (const int*)d_in[0];
    const float* pos   = (const float*)d_in[1];
    const int*   ei    = (const int*)d_in[2];
    const float* freq  = (const float*)d_in[3];
    const float* emb   = (const float*)d_in[4];
    const float* W_rbf = (const float*)d_in[5];
    const float* b_rbf = (const float*)d_in[6];
    const float* W_lin = (const float*)d_in[7];
    const float* b_lin = (const float*)d_in[8];

    int N    = in_sizes[0];
    int E    = in_sizes[2] / 2;
    int MAXZ = in_sizes[4] / HID;   // 95 == MZ
    float* out = (float*)d_out;

    int N_pad = ((N + 1024) / 1024) * 1024;   // strictly > N so offs[N] is valid
    int NB    = N_pad / 1024;

    char* ws = (char*)d_ws;
    size_t off = 0;
    auto alloc = [&](size_t bytes) { char* p = ws + off; off = (off + bytes + 255) & ~(size_t)255; return p; };
    int*   cnt     = (int*)alloc((size_t)N_pad * 4);
    int*   offs    = (int*)alloc((size_t)N_pad * 4);
    int*   bsum    = (int*)alloc((size_t)NB * 4);
    int*   rank    = (int*)alloc((size_t)E * 4);
    __hip_bfloat16* Tb = (__hip_bfloat16*)alloc((size_t)2 * MAXZ * HID * 2);
    float* ftab    = (float*)alloc((size_t)(TABN + 1) * HID * 4);
    int*   payload = (int*)alloc((size_t)E * 4);

    hipMemsetAsync(cnt, 0, (size_t)N_pad * 4, stream);

    int nBuild = 2 * MAXZ + (TABN + 1) + (E + HID - 1) / HID;
    build1<<<nBuild, HID, 0, stream>>>(emb, W_lin, freq, W_rbf, b_rbf, b_lin,
                                       Tb, ftab, ei + E, cnt, rank, MAXZ, E);
    scan1<<<NB, 256, 0, stream>>>(cnt, offs, bsum);
    scan2<<<1, 256, 0, stream>>>(bsum, NB);
    scan3<<<NB, 256, 0, stream>>>(offs, bsum);
    scatter_k<<<(E + 255) / 256, 256, 0, stream>>>(ei, pos, z, offs, rank, payload, E);
    gather_k<<<512, 1024, 0, stream>>>(offs, payload, (const uint32*)Tb, ftab, out, N);
}

// Round 7
// 190.863 us; speedup vs baseline: 2.1653x; 1.1220x over previous
//
#include <hip/hip_runtime.h>
#include <hip/hip_bf16.h>
#include <math.h>

#define HID 128
#define NRAD 6
#define TABN 4096          // nearest-neighbor table rows 0..TABN (row TABN = 0, x>=1 gate)
#define CUTOFF_INV 0.2f
#define MZ 95
#define PAD 32             // padded-CSR slots per node (one 128B line); overflow -> spill list
#define OVF_CAP 65536

typedef unsigned int uint32;

// ---------- K1 (fused): bf16 T1(+b_lin)/T2 + ftab + edge pass (count + padded scatter) ----------
__global__ void build1(const float* __restrict__ emb, const float* __restrict__ W_lin,
                       const float* __restrict__ freq, const float* __restrict__ W_rbf,
                       const float* __restrict__ b_rbf, const float* __restrict__ b_lin,
                       const int* __restrict__ ei, const float* __restrict__ pos,
                       const int* __restrict__ z,
                       __hip_bfloat16* __restrict__ Tb, float* __restrict__ ftab,
                       int* __restrict__ cnt, int* __restrict__ payload,
                       int* __restrict__ ovfcnt, int2* __restrict__ ovfbuf,
                       int MAXZ, int E) {
    __shared__ float sh[HID];
    int h   = threadIdx.x;
    int bid = blockIdx.x;
    int nT  = 2 * MAXZ;
    int nF  = TABN + 1;
    if (bid < nT) {
        int zz = bid >> 1, s = bid & 1;
        sh[h] = emb[zz * HID + h];
        __syncthreads();
        const float* W = W_lin + (size_t)s * HID * HID;
        float acc = (s == 0) ? b_lin[h] : 0.f;   // fold bias into T1
#pragma unroll 8
        for (int k = 0; k < HID; ++k) acc = fmaf(sh[k], W[k * HID + h], acc);
        Tb[(size_t)(s * MAXZ + zz) * HID + h] = __float2bfloat16(acc);
    } else if (bid < nT + nF) {
        int t = bid - nT;   // 0..TABN
        float rbf[NRAD];
        if (t == 0) {
#pragma unroll
            for (int k = 0; k < NRAD; ++k) rbf[k] = freq[k];   // lim x->0 env*sin(fx)=f
        } else if (t >= TABN) {
#pragma unroll
            for (int k = 0; k < NRAD; ++k) rbf[k] = 0.f;       // envelope gate x>=1
        } else {
            float x  = (float)t / (float)TABN;
            float x2 = x * x, x5 = x2 * x2 * x;
            float env = 1.f / x + x5 * (-28.f + x * (48.f + x * (-21.f)));
#pragma unroll
            for (int k = 0; k < NRAD; ++k) rbf[k] = env * sinf(freq[k] * x);
        }
        float pre = b_rbf[h];
#pragma unroll
        for (int k = 0; k < NRAD; ++k) pre = fmaf(rbf[k], W_rbf[k * HID + h], pre);
        sh[h] = pre / (1.f + __expf(-pre));   // precise silu (once per table row)
        __syncthreads();
        const float* W3 = W_lin + (size_t)2 * HID * HID;
        float acc = 0.f;
#pragma unroll 8
        for (int k = 0; k < HID; ++k) acc = fmaf(sh[k], W3[k * HID + h], acc);
        ftab[(size_t)t * HID + h] = acc;
    } else {
        // edge pass: distance -> table index, rank via one atomic, direct padded write
        int e = (bid - nT - nF) * HID + h;
        if (e < E) {
            int i = ei[e];
            int j = ei[E + e];
            float dx = pos[3 * i]     - pos[3 * j];
            float dy = pos[3 * i + 1] - pos[3 * j + 1];
            float dz = pos[3 * i + 2] - pos[3 * j + 2];
            float d  = sqrtf(dx * dx + dy * dy + dz * dz);
            float u  = fminf(d * CUTOFF_INV, 1.0f) * (float)TABN;
            int   ti = (int)(u + 0.5f);          // nearest
            if (ti > TABN) ti = TABN;
            int pl = ti | (z[i] << 13) | (z[j] << 20);
            int r  = atomicAdd(&cnt[j], 1);
            if (r < PAD) {
                payload[j * PAD + r] = pl;
            } else {
                int o = atomicAdd(ovfcnt, 1);
                if (o < OVF_CAP) ovfbuf[o] = make_int2(j, pl);
            }
        }
    }
}

// ---------- gather: 1 wave per node, padded row, readlane broadcast ----------
__launch_bounds__(1024)
__global__ void gather_k(const int* __restrict__ cnt, const int* __restrict__ payload,
                         const uint32* __restrict__ Tb32, const float* __restrict__ ftab,
                         float* __restrict__ out, int N) {
    __shared__ uint32 sT[2 * MZ * (HID / 2)];    // 48640 B, bf16 pairs
    int tid = threadIdx.x;
    for (int k = tid; k < 2 * MZ * (HID / 2); k += 1024) sT[k] = Tb32[k];
    __syncthreads();

    int lane = tid & 63, wv = tid >> 6;          // 16 waves/block, 1 node/wave
    int h2   = lane * 2;
    const uint32* sT2 = sT + MZ * (HID / 2);
    const float*  ft  = ftab + h2;
    int nCh = (N + 15) >> 4;

    for (int ch = blockIdx.x; ch < nCh; ch += gridDim.x) {
        int n = (ch << 4) + wv;
        if (n >= N) continue;
        int deg = cnt[n];                        // true degree (may exceed PAD)
        int cb  = deg < PAD ? deg : PAD;
        int plv = payload[n * PAD + (lane & (PAD - 1))];   // one line, coalesced

        float a0 = 0.f, a1 = 0.f;
        for (int k = 0; k < cb; ++k) {
            int pl = __builtin_amdgcn_readlane(plv, k);    // SGPR broadcast
            int ti = pl & 0x1FFF;
            int zi = (pl >> 13) & 0x7F;
            int zj = (pl >> 20) & 0x7F;
            float2 f  = *(const float2*)(ft + (size_t)ti * HID);
            uint32 u1 = sT[zi * (HID / 2) + lane];
            uint32 u2 = sT2[zj * (HID / 2) + lane];
            float p0 = __uint_as_float(u1 << 16)         + __uint_as_float(u2 << 16)         + f.x;
            float p1 = __uint_as_float(u1 & 0xFFFF0000u) + __uint_as_float(u2 & 0xFFFF0000u) + f.y;
            a0 = fmaf(p0, __builtin_amdgcn_rcpf(1.f + __expf(-p0)), a0);
            a1 = fmaf(p1, __builtin_amdgcn_rcpf(1.f + __expf(-p1)), a1);
        }
        float s = (deg > 0) ? 1.0f / (float)deg : 0.0f;
        float2 o; o.x = a0 * s; o.y = a1 * s;
        *(float2*)(out + (size_t)n * HID + h2) = o;
    }
}

// ---------- fixup: process spill list (empty in practice), atomic add of v/deg ----------
__global__ void fixup_k(const int* __restrict__ ovfcnt, const int2* __restrict__ ovfbuf,
                        const int* __restrict__ cnt, const uint32* __restrict__ Tb32,
                        const float* __restrict__ ftab, float* __restrict__ out, int MAXZ) {
    int nov = *ovfcnt;
    if (nov > OVF_CAP) nov = OVF_CAP;
    int total = nov * 64;
    int stride = gridDim.x * blockDim.x;
    const uint32* T2b = Tb32 + MAXZ * (HID / 2);
    for (int u = blockIdx.x * blockDim.x + threadIdx.x; u < total; u += stride) {
        int ent = u >> 6, lane = u & 63;
        int2 v = ovfbuf[ent];
        int j  = v.x, pl = v.y;
        int ti = pl & 0x1FFF;
        int zi = (pl >> 13) & 0x7F;
        int zj = (pl >> 20) & 0x7F;
        float2 f  = *(const float2*)(ftab + (size_t)ti * HID + lane * 2);
        uint32 u1 = Tb32[zi * (HID / 2) + lane];
        uint32 u2 = T2b[zj * (HID / 2) + lane];
        float p0 = __uint_as_float(u1 << 16)         + __uint_as_float(u2 << 16)         + f.x;
        float p1 = __uint_as_float(u1 & 0xFFFF0000u) + __uint_as_float(u2 & 0xFFFF0000u) + f.y;
        float s  = 1.0f / (float)max(cnt[j], 1);
        atomicAdd(&out[(size_t)j * HID + lane * 2],     p0 * __builtin_amdgcn_rcpf(1.f + __expf(-p0)) * s);
        atomicAdd(&out[(size_t)j * HID + lane * 2 + 1], p1 * __builtin_amdgcn_rcpf(1.f + __expf(-p1)) * s);
    }
}

// ---------- launch ----------
extern "C" void kernel_launch(void* const* d_in, const int* in_sizes, int n_in,
                              void* d_out, int out_size, void* d_ws, size_t ws_size,
                              hipStream_t stream) {
    const int*   z     = (const int*)d_in[0];
    const float* pos   = (const float*)d_in[1];
    const int*   ei    = (const int*)d_in[2];
    const float* freq  = (const float*)d_in[3];
    const float* emb   = (const float*)d_in[4];
    const float* W_rbf = (const float*)d_in[5];
    const float* b_rbf = (const float*)d_in[6];
    const float* W_lin = (const float*)d_in[7];
    const float* b_lin = (const float*)d_in[8];

    int N    = in_sizes[0];
    int E    = in_sizes[2] / 2;
    int MAXZ = in_sizes[4] / HID;   // 95 == MZ
    float* out = (float*)d_out;

    int N_pad = ((N + 1024) / 1024) * 1024;   // multiple of 1024, strictly > N

    char* ws = (char*)d_ws;
    size_t off = 0;
    auto alloc = [&](size_t bytes) { char* p = ws + off; off = (off + bytes + 255) & ~(size_t)255; return p; };
    int*   cnt     = (int*)alloc((size_t)N_pad * 4);     // N_pad*4 is 256-aligned
    int*   ovfcnt  = (int*)alloc(256);                   // adjacent to cnt for one memset
    __hip_bfloat16* Tb = (__hip_bfloat16*)alloc((size_t)2 * MAXZ * HID * 2);
    float* ftab    = (float*)alloc((size_t)(TABN + 1) * HID * 4);
    int*   payload = (int*)alloc((size_t)N_pad * PAD * 4);
    int2*  ovfbuf  = (int2*)alloc((size_t)OVF_CAP * 8);

    hipMemsetAsync(cnt, 0, (size_t)N_pad * 4 + 256, stream);   // zeros cnt + ovfcnt

    int nBuild = 2 * MAXZ + (TABN + 1) + (E + HID - 1) / HID;
    build1<<<nBuild, HID, 0, stream>>>(emb, W_lin, freq, W_rbf, b_rbf, b_lin,
                                       ei, pos, z, Tb, ftab, cnt, payload,
                                       ovfcnt, ovfbuf, MAXZ, E);
    gather_k<<<512, 1024, 0, stream>>>(cnt, payload, (const uint32*)Tb, ftab, out, N);
    fixup_k<<<128, 256, 0, stream>>>(ovfcnt, ovfbuf, cnt, (const uint32*)Tb, ftab, out, MAXZ);
}